// Round 4
// baseline (4605.713 us; speedup 1.0000x reference)
//
#include <hip/hip_runtime.h>
#include <hip/hip_bf16.h>

// Problem constants
#define T_STEPS 64
#define BATCH   1024
#define HID     512
#define GATES   2048          // 4*H
#define KDIM    1024          // IN + H
#define BH      (BATCH*HID)   // 524288
#define THB     (T_STEPS*BATCH*HID)
#define NMG     32            // m-groups (32 rows each)
#define NJB     16            // j-blocks per group (n-tile 128 = 4 gates x 32 j)
#define GRPSZ   16
#define BK      128           // k-chunk
#define LDP     136           // LDS row pitch in shorts (128 + 8 pad -> 2-way-free banks)

typedef __attribute__((ext_vector_type(4))) float f32x4;
typedef __attribute__((ext_vector_type(8))) short short8;

__device__ __forceinline__ float sigmoidf_(float x) { return 1.f / (1.f + __expf(-x)); }

__device__ __forceinline__ unsigned short bf16b(float x) {
    __hip_bfloat16 b = __float2bfloat16(x);
    return *reinterpret_cast<unsigned short*>(&b);
}

// ---- fence-free cross-block coherence (unchanged from passing round 3) ----
__device__ __forceinline__ void sig_slot(unsigned* slot) {
    __syncthreads();                       // all block stores acked (vmcnt(0) at barrier)
    if (threadIdx.x == 0)
        __hip_atomic_store(slot, 1u, __ATOMIC_RELAXED, __HIP_MEMORY_SCOPE_AGENT);
}
__device__ __forceinline__ void wait_slots(unsigned* slots) {
    unsigned* p = slots + (threadIdx.x & (GRPSZ - 1));
    for (;;) {
        unsigned v = __hip_atomic_load(p, __ATOMIC_RELAXED, __HIP_MEMORY_SCOPE_AGENT);
        if (__all(v != 0)) break;
        __builtin_amdgcn_s_sleep(4);
    }
    __syncthreads();                       // joins waves + compiler memory barrier
}

// packed bf16 pair store (even lane stores {own j, partner j+1}) at agent scope
__device__ __forceinline__ void store_pair(__hip_bfloat16* base, int m, int j, float v, int lane) {
    float o = __shfl_xor(v, 1);
    if (!(lane & 1)) {
        unsigned pk = (unsigned)bf16b(v) | ((unsigned)bf16b(o) << 16);
        __hip_atomic_store((unsigned*)(base + (size_t)m * HID + j), pk,
                           __ATOMIC_RELAXED, __HIP_MEMORY_SCOPE_AGENT);
    }
}

// ---- 16B asm loads: sc (coherence-point, L2-bypass) and cached ----
__device__ __forceinline__ void ld_sc(short8& d, const __hip_bfloat16* p) {
    asm volatile("global_load_dwordx4 %0, %1, off sc0 sc1" : "=v"(d) : "v"(p));
}
__device__ __forceinline__ void ld_ca(short8& d, const __hip_bfloat16* p) {
    asm volatile("global_load_dwordx4 %0, %1, off" : "=v"(d) : "v"(p));
}

struct Regs { short8 a[2]; short8 w[8]; };

// counted vmcnt wait; ties chunk regs so no copy can read them before data lands
#define VMWAIT(N, R) asm volatile("s_waitcnt vmcnt(" #N ")" : \
    "+v"((R).a[0]), "+v"((R).a[1]), "+v"((R).w[0]), "+v"((R).w[1]), "+v"((R).w[2]), \
    "+v"((R).w[3]), "+v"((R).w[4]), "+v"((R).w[5]), "+v"((R).w[6]), "+v"((R).w[7]) :: "memory")

#define LGKM0_FENCE() asm volatile("s_waitcnt lgkmcnt(0)" ::: "memory")
#define MEMFENCE()    asm volatile("" ::: "memory")

// issue one chunk: 2x16B A-loads (A array is [1024][512] bf16) + 8x16B W-loads
template<bool ASC>
__device__ __forceinline__ void issue_chunk(Regs& R, const __hip_bfloat16* Ab, int kh,
                                            const __hip_bfloat16* Wb, int k0,
                                            int m0, int jb, int tid)
{
#pragma unroll
    for (int i = 0; i < 2; ++i) {
        int q = tid + i * 256, rr = q >> 4, s = q & 15;
        const __hip_bfloat16* p = Ab + (size_t)(m0 + rr) * HID + kh + s * 8;
        if (ASC) ld_sc(R.a[i], p); else ld_ca(R.a[i], p);
    }
#pragma unroll
    for (int i = 0; i < 8; ++i) {
        int q = tid + i * 256, rr = q >> 4, s = q & 15;
        int wrow = (rr >> 5) * 512 + jb * 32 + (rr & 31);
        ld_ca(R.w[i], Wb + (size_t)wrow * KDIM + k0 + s * 8);
    }
}

__device__ __forceinline__ void write_lds(const Regs& R, short* As, short* Ws, int tid) {
#pragma unroll
    for (int i = 0; i < 2; ++i) {
        int q = tid + i * 256, rr = q >> 4, s = q & 15;
        *(short8*)&As[rr * LDP + s * 8] = R.a[i];
    }
#pragma unroll
    for (int i = 0; i < 8; ++i) {
        int q = tid + i * 256, rr = q >> 4, s = q & 15;
        *(short8*)&Ws[rr * LDP + s * 8] = R.w[i];
    }
}

__device__ __forceinline__ void mfma_chunk(const short* As, const short* Ws,
                                           int wm, int wj, int lr, int lq, f32x4 acc[4]) {
#pragma unroll
    for (int kk = 0; kk < BK; kk += 32) {
        short8 a = *(const short8*)&As[(wm * 16 + lr) * LDP + kk + lq * 8];
#pragma unroll
        for (int g = 0; g < 4; ++g) {
            short8 w = *(const short8*)&Ws[(g * 32 + wj * 16 + lr) * LDP + kk + lq * 8];
            acc[g] = __builtin_amdgcn_mfma_f32_16x16x32_bf16(a, w, acc[g], 0, 0, 0);
        }
    }
}

// 32m x 128n GEMM over K=1024: 8 chunks, depth-1 reg pipeline, counted vmcnt,
// raw s_barrier (no vmcnt drain) with asm fences on both sides.
template<bool SC_LO>
__device__ void gemm_run(const __hip_bfloat16* Alo, const __hip_bfloat16* Ahi,
                         const __hip_bfloat16* Wb, short* As, short* Ws,
                         int tid, int wm, int wj, int lr, int lq, int m0, int jb, f32x4 acc[4])
{
    Regs R[2];
    issue_chunk<SC_LO>(R[0], Alo, 0, Wb, 0, m0, jb, tid);
#pragma unroll
    for (int c = 0; c < 8; ++c) {
        if (c < 7) {
            const int cn = c + 1;
            if (cn < 4) issue_chunk<SC_LO>(R[cn & 1], Alo, cn * BK, Wb, cn * BK, m0, jb, tid);
            else        issue_chunk<true >(R[cn & 1], Ahi, (cn - 4) * BK, Wb, cn * BK, m0, jb, tid);
            VMWAIT(10, R[c & 1]);
        } else {
            VMWAIT(0, R[c & 1]);
        }
        write_lds(R[c & 1], As, Ws, tid);
        LGKM0_FENCE();
        __builtin_amdgcn_s_barrier();
        MEMFENCE();
        mfma_chunk(As, Ws, wm, wj, lr, lq, acc);
        LGKM0_FENCE();
        __builtin_amdgcn_s_barrier();
        MEMFENCE();
    }
}

// ---------------- weight packing: [w_ih | w_hh] -> bf16 [2048][1024], bias sum ----------------
__global__ void pack_weights(const float* __restrict__ wih0, const float* __restrict__ whh0,
                             const float* __restrict__ wih1, const float* __restrict__ whh1,
                             const float* __restrict__ bih0, const float* __restrict__ bhh0,
                             const float* __restrict__ bih1, const float* __restrict__ bhh1,
                             __hip_bfloat16* __restrict__ w0p, __hip_bfloat16* __restrict__ w1p,
                             float* __restrict__ b0, float* __restrict__ b1)
{
    int idx = blockIdx.x * 256 + threadIdx.x;   // over 2048*1024
    int n = idx >> 10, k = idx & 1023;
    float v0 = (k < 512) ? wih0[n * 512 + k] : whh0[n * 512 + (k - 512)];
    float v1 = (k < 512) ? wih1[n * 512 + k] : whh1[n * 512 + (k - 512)];
    w0p[idx] = __float2bfloat16(v0);
    w1p[idx] = __float2bfloat16(v1);
    if (idx < GATES) {
        b0[idx] = bih0[idx] + bhh0[idx];
        b1[idx] = bih1[idx] + bhh1[idx];
    }
}

// ---------------- latent f32 -> bf16 pre-pack (once; removes per-step conversion) ----------------
__global__ void pack_latent(const float* __restrict__ lat, __hip_bfloat16* __restrict__ latp)
{
    size_t base = ((size_t)blockIdx.x * 256 + threadIdx.x) * 8;
    f32x4 v0 = *(const f32x4*)&lat[base];
    f32x4 v1 = *(const f32x4*)&lat[base + 4];
    short8 s;
    s[0] = (short)bf16b(v0[0]); s[1] = (short)bf16b(v0[1]);
    s[2] = (short)bf16b(v0[2]); s[3] = (short)bf16b(v0[3]);
    s[4] = (short)bf16b(v1[0]); s[5] = (short)bf16b(v1[1]);
    s[6] = (short)bf16b(v1[2]); s[7] = (short)bf16b(v1[3]);
    *(short8*)&latp[base] = s;
}

// =====================================================================================
// Persistent LSTM scan: 512 blocks (2/CU), tile 32m x 128n (4 gates x 32 j), BK=128.
// Group = blocks [mg*16, mg*16+16): 16 j-blocks of one 32-row m-slice; each block runs
// BOTH layers all 64 steps. Flags identical to round 3 (GRPSZ now 16).
// =====================================================================================
__global__ __launch_bounds__(256, 2) void lstm_scan(
    const __hip_bfloat16* __restrict__ latp, const float* __restrict__ h_t, const float* __restrict__ c_t,
    const int* __restrict__ reset_mask, const int* __restrict__ clear_mask,
    const float* __restrict__ noise_std, const float* __restrict__ noise,
    const __hip_bfloat16* __restrict__ w0p, const __hip_bfloat16* __restrict__ w1p,
    const float* __restrict__ b0, const float* __restrict__ b1,
    __hip_bfloat16* h0p,   // [2][1024][512] bf16
    __hip_bfloat16* h1p,   // [2][1024][512] bf16
    __hip_bfloat16* h0,    // [1024][512] bf16
    unsigned* flags, float* __restrict__ out)
{
    __shared__ short As[32 * LDP];
    __shared__ short Ws[128 * LDP];
    const int tid  = threadIdx.x;
    const int lane = tid & 63;
    const int wave = tid >> 6;
    const int lr   = lane & 15;
    const int lq   = lane >> 4;
    const int wm   = wave & 1;          // m-16-half
    const int wj   = wave >> 1;         // j-16-half
    const int b    = blockIdx.x;
    const int mg   = b >> 4;            // 0..31, contiguous group
    const int jb   = b & 15;            // b%8 == jb%8 -> 2 jb per XCD -> 1MB W L2-hot
    const int m0   = mg * 32;
    const int j    = jb * 32 + wj * 16 + lr;

    unsigned* fX = flags;                                   // [64][NMG][NJB]
    unsigned* fY = flags + (size_t)T_STEPS * NMG * NJB;

    const float bi0 = b0[j],        bf0 = b0[512 + j];
    const float bg0 = b0[1024 + j], bo0 = b0[1536 + j];
    const float bi1 = b1[j],        bf1 = b1[512 + j];
    const float bg1 = b1[1024 + j], bo1 = b1[1536 + j];

    float cs0[4], cs1[4];

    // ---------------- init: t=0 prep for both layers ----------------
#pragma unroll
    for (int r = 0; r < 4; ++r) {
        int m   = m0 + wm * 16 + lq * 4 + r;
        int idx = m * HID + j;
        bool msk = (reset_mask[m * T_STEPS] | clear_mask[m * T_STEPS]) != 0;
        float s  = noise_std[m * T_STEPS];
        float nv0 = noise[(size_t)m * HID + j] * s;             // noise[0][0][m][j]
        float nv1 = noise[((size_t)BATCH + m) * HID + j] * s;   // noise[0][1][m][j]
        float hp0 = (msk ? 0.f : h_t[idx]) + nv0;
        cs0[r] = (msk ? 0.f : c_t[idx]) + nv0;
        float hp1 = (msk ? 0.f : h_t[BH + idx]) + nv1;
        cs1[r] = (msk ? 0.f : c_t[BH + idx]) + nv1;
        store_pair(h0p, m, j, hp0, lane);                       // parity 0
        store_pair(h1p, m, j, hp1, lane);                       // parity 0
    }
    sig_slot(&fX[((size_t)0 * NMG + mg) * NJB + jb]);

    for (int t = 0; t < T_STEPS; ++t) {
        const int p = t & 1;
        wait_slots(&fX[((size_t)t * NMG + mg) * NJB]);

        // ---- layer 0: A = [latent_bf16(t) | h0p[p]] ----
        f32x4 acc[4];
#pragma unroll
        for (int g = 0; g < 4; ++g) acc[g] = (f32x4){0.f, 0.f, 0.f, 0.f};
        gemm_run<false>(latp + (size_t)t * BH, h0p + (size_t)p * BH, w0p,
                        As, Ws, tid, wm, wj, lr, lq, m0, jb, acc);

        float hv0[4], cv0[4];
#pragma unroll
        for (int r = 0; r < 4; ++r) {
            float gi = acc[0][r] + bi0, gf = acc[1][r] + bf0;
            float gg = acc[2][r] + bg0, go = acc[3][r] + bo0;
            float cn = sigmoidf_(gf) * cs0[r] + sigmoidf_(gi) * tanhf(gg);
            hv0[r] = sigmoidf_(go) * tanhf(cn);
            cv0[r] = cn;
        }
#pragma unroll
        for (int r = 0; r < 4; ++r) {
            int m = m0 + wm * 16 + lq * 4 + r;
            store_pair(h0, m, j, hv0[r], lane);
            if (t < T_STEPS - 1) {
                int tn = t + 1;
                bool msk = (reset_mask[m * T_STEPS + tn] | clear_mask[m * T_STEPS + tn]) != 0;
                float nv = noise[((size_t)(tn * 2) * BATCH + m) * HID + j] * noise_std[m * T_STEPS + tn];
                float hp = (msk ? 0.f : hv0[r]) + nv;
                cs0[r] = (msk ? 0.f : cv0[r]) + nv;
                store_pair(h0p + (size_t)(p ^ 1) * BH, m, j, hp, lane);
            } else {
                int idx = m * HID + j;
                out[THB + idx]          = hv0[r];
                out[THB + 2 * BH + idx] = cv0[r];
            }
        }
        sig_slot(&fY[((size_t)t * NMG + mg) * NJB + jb]);
        wait_slots(&fY[((size_t)t * NMG + mg) * NJB]);

        // ---- layer 1: A = [h0 | h1p[p]] (both halves via sc path) ----
#pragma unroll
        for (int g = 0; g < 4; ++g) acc[g] = (f32x4){0.f, 0.f, 0.f, 0.f};
        gemm_run<true>(h0, h1p + (size_t)p * BH, w1p,
                       As, Ws, tid, wm, wj, lr, lq, m0, jb, acc);

#pragma unroll
        for (int r = 0; r < 4; ++r) {
            float gi = acc[0][r] + bi1, gf = acc[1][r] + bf1;
            float gg = acc[2][r] + bg1, go = acc[3][r] + bo1;
            float cn = sigmoidf_(gf) * cs1[r] + sigmoidf_(gi) * tanhf(gg);
            float hn = sigmoidf_(go) * tanhf(cn);
            int m   = m0 + wm * 16 + lq * 4 + r;
            int idx = m * HID + j;
            out[(size_t)t * BH + idx] = hn;
            if (t < T_STEPS - 1) {
                int tn = t + 1;
                bool msk = (reset_mask[m * T_STEPS + tn] | clear_mask[m * T_STEPS + tn]) != 0;
                float nv = noise[((size_t)(tn * 2 + 1) * BATCH + m) * HID + j] * noise_std[m * T_STEPS + tn];
                float hp = (msk ? 0.f : hn) + nv;
                cs1[r] = (msk ? 0.f : cn) + nv;
                store_pair(h1p + (size_t)(p ^ 1) * BH, m, j, hp, lane);
            } else {
                out[THB + BH + idx]     = hn;
                out[THB + 3 * BH + idx] = cn;
            }
        }
        if (t < T_STEPS - 1)
            sig_slot(&fX[((size_t)(t + 1) * NMG + mg) * NJB + jb]);
    }
}

extern "C" void kernel_launch(void* const* d_in, const int* in_sizes, int n_in,
                              void* d_out, int out_size, void* d_ws, size_t ws_size,
                              hipStream_t stream)
{
    const float* latent     = (const float*)d_in[0];
    const float* h_t        = (const float*)d_in[1];
    const float* c_t        = (const float*)d_in[2];
    const int*   reset_mask = (const int*)d_in[3];   // (1,B,T,1) flat b*T+t
    const int*   clear_mask = (const int*)d_in[4];   // (B,T)     flat b*T+t
    const float* noise_std  = (const float*)d_in[5]; // (B,T)     flat b*T+t
    const float* noise      = (const float*)d_in[6]; // (T,L,B,H)
    const float* wih0 = (const float*)d_in[7];
    const float* whh0 = (const float*)d_in[8];
    const float* bih0 = (const float*)d_in[9];
    const float* bhh0 = (const float*)d_in[10];
    const float* wih1 = (const float*)d_in[11];
    const float* whh1 = (const float*)d_in[12];
    const float* bih1 = (const float*)d_in[13];
    const float* bhh1 = (const float*)d_in[14];
    float* out = (float*)d_out;

    char* ws = (char*)d_ws;
    size_t off = 0;
    auto alloc = [&](size_t bytes) -> void* {
        void* p = ws + off;
        off += (bytes + 255) & ~(size_t)255;
        return p;
    };
    __hip_bfloat16* w0p  = (__hip_bfloat16*)alloc((size_t)GATES * KDIM * 2);
    __hip_bfloat16* w1p  = (__hip_bfloat16*)alloc((size_t)GATES * KDIM * 2);
    float* b0 = (float*)alloc(GATES * 4);
    float* b1 = (float*)alloc(GATES * 4);
    __hip_bfloat16* latp = (__hip_bfloat16*)alloc((size_t)THB * 2);
    __hip_bfloat16* h0p  = (__hip_bfloat16*)alloc((size_t)2 * BH * 2);
    __hip_bfloat16* h1p  = (__hip_bfloat16*)alloc((size_t)2 * BH * 2);
    __hip_bfloat16* h0   = (__hip_bfloat16*)alloc((size_t)BH * 2);
    size_t flag_bytes = (size_t)2 * T_STEPS * NMG * NJB * sizeof(unsigned);
    unsigned* flags = (unsigned*)alloc(flag_bytes);

    hipMemsetAsync(flags, 0, flag_bytes, stream);

    pack_weights<<<(GATES * KDIM) / 256, 256, 0, stream>>>(
        wih0, whh0, wih1, whh1, bih0, bhh0, bih1, bhh1, w0p, w1p, b0, b1);
    pack_latent<<<THB / 2048, 256, 0, stream>>>(latent, latp);

    lstm_scan<<<NMG * NJB, 256, 0, stream>>>(
        latp, h_t, c_t, reset_mask, clear_mask, noise_std, noise,
        w0p, w1p, b0, b1, h0p, h1p, h0, flags, out);
}